// Round 4
// baseline (746.606 us; speedup 1.0000x reference)
//
#include <hip/hip_runtime.h>

#define D_MODEL 4096
#define VOCAB 50257
#define VP_ST 50432          // plane stride (= 197*256, multiple of 256)
#define NUM_SEQS 32
#define NSLICE 16

// ws layout:
//   [0,128)            idx[32] int
//   [1024, +512KB)     hT [4096][32] float (transposed gathered hidden rows)
//   [0x90000, +4KB)    partials [32][NSLICE] u64 argmax keys
//   [1MB, ...]         part [KSPLIT][32][VP_ST] float partial-logit planes
//                      KSPLIT = 32 if ws fits (206 MB), else 16 (103 MB)

__global__ void k_prep(const int* __restrict__ lens, int* __restrict__ idx) {
  if (threadIdx.x == 0) {
    int run = 0;
    for (int s = 0; s < NUM_SEQS; ++s) { run += lens[s]; idx[s] = run - 1; }
  }
}

// 256 blocks x 512 threads; block b covers k in [b*16, b*16+16)
__global__ void k_gather(const float* __restrict__ hs, const int* __restrict__ idx,
                         float* __restrict__ hT) {
  int t = threadIdx.x;
  int s = t & 31;
  int k = blockIdx.x * 16 + (t >> 5);
  int row = idx[s];
  hT[k * 32 + s] = hs[(size_t)row * D_MODEL + k];
}

// grid (197, KSPLIT) x 128 threads (2 waves). Each lane owns vocab rows v0 and
// v0+64 (256 rows/block): every LDS h-broadcast feeds 2 FMAs, and 128 B/lane of
// W is in flight (reg-double-buffered 8-k chunks).
__global__ __launch_bounds__(128, 4) void k_logits_part(
    const float* __restrict__ W, const float* __restrict__ hT,
    float* __restrict__ part, int kc) {
  extern __shared__ float hs_lds[];  // kc*32 floats, layout [k][s]
  const int k0 = blockIdx.y * kc;

  {  // stage h chunk (linear copy)
    const float4* src = (const float4*)(hT + (size_t)k0 * NUM_SEQS);
    float4* dst = (float4*)hs_lds;
    const int n4 = kc * NUM_SEQS / 4;
    for (int j = threadIdx.x; j < n4; j += 128) dst[j] = src[j];
  }
  __syncthreads();

  const int lane = threadIdx.x & 63;
  const int w = threadIdx.x >> 6;
  const int v0 = blockIdx.x * 256 + w * 128 + lane;
  const int v1 = v0 + 64;
  const int vc0 = v0 < VOCAB ? v0 : VOCAB - 1;
  const int vc1 = v1 < VOCAB ? v1 : VOCAB - 1;
  const float4* wr0 = (const float4*)(W + (size_t)vc0 * D_MODEL + k0);
  const float4* wr1 = (const float4*)(W + (size_t)vc1 * D_MODEL + k0);
  const float4* h4 = (const float4*)hs_lds;

  float acc0[NUM_SEQS], acc1[NUM_SEQS];
#pragma unroll
  for (int s = 0; s < NUM_SEQS; ++s) { acc0[s] = 0.f; acc1[s] = 0.f; }

  float4 c00 = wr0[0], c01 = wr0[1];   // current 8-k chunk, row 0
  float4 c10 = wr1[0], c11 = wr1[1];   // current 8-k chunk, row 1

#pragma unroll 1
  for (int kq = 0; kq < kc; kq += 8) {
    const int nq = (kq + 8 < kc) ? (kq + 8) : 0;  // wrap: last iter reloads 0
    float4 n00 = wr0[(nq >> 2) + 0], n01 = wr0[(nq >> 2) + 1];
    float4 n10 = wr1[(nq >> 2) + 0], n11 = wr1[(nq >> 2) + 1];
#pragma unroll
    for (int kk = 0; kk < 8; ++kk) {
      const float4 wq0 = (kk < 4) ? c00 : c01;
      const float4 wq1 = (kk < 4) ? c10 : c11;
      const int c = kk & 3;
      const float w0 = (c == 0) ? wq0.x : (c == 1) ? wq0.y : (c == 2) ? wq0.z : wq0.w;
      const float w1 = (c == 0) ? wq1.x : (c == 1) ? wq1.y : (c == 2) ? wq1.z : wq1.w;
#pragma unroll
      for (int sq = 0; sq < 8; ++sq) {
        const float4 hq = h4[(kq + kk) * 8 + sq];  // uniform addr -> broadcast
        acc0[sq * 4 + 0] = fmaf(w0, hq.x, acc0[sq * 4 + 0]);
        acc0[sq * 4 + 1] = fmaf(w0, hq.y, acc0[sq * 4 + 1]);
        acc0[sq * 4 + 2] = fmaf(w0, hq.z, acc0[sq * 4 + 2]);
        acc0[sq * 4 + 3] = fmaf(w0, hq.w, acc0[sq * 4 + 3]);
        acc1[sq * 4 + 0] = fmaf(w1, hq.x, acc1[sq * 4 + 0]);
        acc1[sq * 4 + 1] = fmaf(w1, hq.y, acc1[sq * 4 + 1]);
        acc1[sq * 4 + 2] = fmaf(w1, hq.z, acc1[sq * 4 + 2]);
        acc1[sq * 4 + 3] = fmaf(w1, hq.w, acc1[sq * 4 + 3]);
      }
    }
    c00 = n00; c01 = n01; c10 = n10; c11 = n11;
  }

  float* p = part + (size_t)blockIdx.y * NUM_SEQS * VP_ST;
  if (v0 < VOCAB) {
#pragma unroll
    for (int s = 0; s < NUM_SEQS; ++s) p[(size_t)s * VP_ST + v0] = acc0[s];
  }
  if (v1 < VOCAB) {
#pragma unroll
    for (int s = 0; s < NUM_SEQS; ++s) p[(size_t)s * VP_ST + v1] = acc1[s];
  }
}

// grid (NSLICE, 32) x 256: block = (vocab slice, seq). Sums ksplit planes in
// fixed order (deterministic); only reads v < VOCAB (pad never written).
__global__ __launch_bounds__(256) void k_part_argmax(
    const float* __restrict__ part, unsigned long long* __restrict__ partials,
    int ksplit) {
  const int slice = blockIdx.x, s = blockIdx.y;
  const int v0 = slice * (VP_ST / NSLICE);
  const int v1 = min(VOCAB, v0 + (VP_ST / NSLICE));
  unsigned long long best = 0ull;
  for (int v = v0 + threadIdx.x; v < v1; v += 256) {
    float x = 0.f;
#pragma unroll 1
    for (int p = 0; p < ksplit; ++p)
      x += part[((size_t)p * NUM_SEQS + s) * VP_ST + v];
    unsigned u = __float_as_uint(x);
    u = (u & 0x80000000u) ? ~u : (u | 0x80000000u);
    unsigned long long key = ((unsigned long long)u << 32) | (unsigned)(~v);
    if (key > best) best = key;
  }
#pragma unroll
  for (int off = 32; off > 0; off >>= 1) {
    unsigned long long o = __shfl_xor(best, off, 64);
    if (o > best) best = o;
  }
  __shared__ unsigned long long lred[4];
  if ((threadIdx.x & 63) == 0) lred[threadIdx.x >> 6] = best;
  __syncthreads();
  if (threadIdx.x == 0) {
#pragma unroll
    for (int i = 1; i < 4; ++i) if (lred[i] > best) best = lred[i];
    partials[s * NSLICE + slice] = best;
  }
}

__global__ void k_final(const unsigned long long* __restrict__ partials,
                        int* __restrict__ out) {
  int s = threadIdx.x;
  if (s < NUM_SEQS) {
    unsigned long long best = 0ull;
#pragma unroll
    for (int i = 0; i < NSLICE; ++i) {
      unsigned long long k = partials[s * NSLICE + i];
      if (k > best) best = k;
    }
    out[s] = (int)(~(unsigned)(best & 0xFFFFFFFFull));
  }
}

extern "C" void kernel_launch(void* const* d_in, const int* in_sizes, int n_in,
                              void* d_out, int out_size, void* d_ws, size_t ws_size,
                              hipStream_t stream) {
  const float* hs  = (const float*)d_in[0];   // [16384][4096] f32
  const float* W   = (const float*)d_in[1];   // [50257][4096] f32
  const int* lens  = (const int*)d_in[2];     // [32] i32

  char* ws = (char*)d_ws;
  int* idx = (int*)ws;
  float* hT = (float*)(ws + 1024);
  unsigned long long* partials = (unsigned long long*)(ws + 0x90000);
  float* part = (float*)(ws + (1 << 20));
  int* out = (int*)d_out;

  // pick KSPLIT by available workspace: 32 planes need ~207 MB total
  size_t need32 = (size_t)(1 << 20) + (size_t)32 * NUM_SEQS * VP_ST * sizeof(float);
  int ksplit = (ws_size >= need32) ? 32 : 16;
  int kc = D_MODEL / ksplit;

  k_prep<<<1, 64, 0, stream>>>(lens, idx);
  k_gather<<<D_MODEL / 16, 512, 0, stream>>>(hs, idx, hT);
  dim3 grid(VP_ST / 256, ksplit);
  size_t shmem = (size_t)kc * NUM_SEQS * sizeof(float);
  k_logits_part<<<grid, 128, shmem, stream>>>(W, hT, part, kc);
  dim3 rgrid(NSLICE, NUM_SEQS);
  k_part_argmax<<<rgrid, 256, 0, stream>>>(part, partials, ksplit);
  k_final<<<1, 64, 0, stream>>>(partials, out);
}

// Round 5
// 205.948 us; speedup vs baseline: 3.6252x; 3.6252x over previous
//
#include <hip/hip_runtime.h>
#include <hip/hip_bf16.h>

#define D_MODEL 4096
#define VOCAB 50257
#define NUM_SEQS 32
#define NT 1571  // ceil(VOCAB/32) vocab tiles of 32 rows

typedef __attribute__((ext_vector_type(8))) short bf16x8;
typedef __attribute__((ext_vector_type(16))) float f32x16;

// ws layout:
//   [0,128)              idx[32] int
//   [4096, +256KB)       hBh [512][32][8] short  (h hi bf16, MFMA-B-frag order)
//   [266240, +256KB)     hBl [512][32][8] short  (h lo bf16)
//   [528384, +402KB)     wbest [NT][32] u64 per-tile per-seq argmax keys

__device__ __forceinline__ void cvt2(float f, short* hi, short* lo) {
  union { __hip_bfloat16 b; short s; } h, l;
  h.b = __float2bfloat16(f);                 // RNE
  float hf = __bfloat162float(h.b);
  l.b = __float2bfloat16(f - hf);            // residual, RNE
  *hi = h.s; *lo = l.s;
}

__global__ void k_prep(const int* __restrict__ lens, int* __restrict__ idx) {
  if (threadIdx.x == 0) {
    int run = 0;
    for (int s = 0; s < NUM_SEQS; ++s) { run += lens[s]; idx[s] = run - 1; }
  }
}

// 256 blocks x 512: thread g -> (s = g>>12, k = g&4095). Coalesced hs reads.
__global__ void k_gather(const float* __restrict__ hs, const int* __restrict__ idx,
                         short* __restrict__ hBh, short* __restrict__ hBl) {
  int g = blockIdx.x * 512 + threadIdx.x;
  int s = g >> 12, k = g & 4095;
  float v = hs[(size_t)idx[s] * D_MODEL + k];
  short hi, lo; cvt2(v, &hi, &lo);
  int off = ((k >> 3) * 32 + s) * 8 + (k & 7);  // [k/8][s][k%8]
  hBh[off] = hi; hBl[off] = lo;
}

// grid NT x 64. Wave = one 32-vocab x 32-seq tile, full K=4096.
// A = W tile (lane: row=l&31, k=(l>>5)*8+e), converted f32->bf16 hi/lo on the fly.
// B = h (lane: col(seq)=l&31, k=(l>>5)*8+e) from precomputed hi/lo planes (L2-hot).
// acc split into two chains (hi*hi | hi*lo, lo*hi) to shorten MFMA dependency.
__global__ __launch_bounds__(64) void k_mfma(const float* __restrict__ W,
    const short* __restrict__ hBh, const short* __restrict__ hBl,
    unsigned long long* __restrict__ wbest) {
  const int lane = threadIdx.x;
  const int half = lane >> 5;
  const int r32 = lane & 31;
  const int tile = blockIdx.x;
  const int wrow = min(tile * 32 + r32, VOCAB - 1);
  const float* wp = W + (size_t)wrow * D_MODEL + half * 8;
  const short* bph = hBh + ((size_t)half * 32 + r32) * 8;  // step stride 512 shorts
  const short* bpl = hBl + ((size_t)half * 32 + r32) * 8;

  f32x16 accA, accB;
#pragma unroll
  for (int i = 0; i < 16; ++i) { accA[i] = 0.f; accB[i] = 0.f; }

  // A prefetch depth 2 (HBM stream), B depth 1 (L2 stream)
  float4 a0 = *(const float4*)(wp);
  float4 a1 = *(const float4*)(wp + 4);
  float4 p0 = *(const float4*)(wp + 16);
  float4 p1 = *(const float4*)(wp + 20);
  bf16x8 bh = *(const bf16x8*)(bph);
  bf16x8 bl = *(const bf16x8*)(bpl);

#pragma unroll 1
  for (int t = 0; t < 256; ++t) {
    const int t2 = (t + 2 < 256) ? t + 2 : 0;
    const int t1 = (t + 1 < 256) ? t + 1 : 0;
    float4 n0 = *(const float4*)(wp + 16 * t2);
    float4 n1 = *(const float4*)(wp + 16 * t2 + 4);
    bf16x8 nbh = *(const bf16x8*)(bph + 512 * t1);
    bf16x8 nbl = *(const bf16x8*)(bpl + 512 * t1);

    float fa[8] = {a0.x, a0.y, a0.z, a0.w, a1.x, a1.y, a1.z, a1.w};
    bf16x8 ahi, alo;
#pragma unroll
    for (int e = 0; e < 8; ++e) {
      short hi, lo; cvt2(fa[e], &hi, &lo);
      ahi[e] = hi; alo[e] = lo;
    }

    accA = __builtin_amdgcn_mfma_f32_32x32x16_bf16(ahi, bh, accA, 0, 0, 0);
    accB = __builtin_amdgcn_mfma_f32_32x32x16_bf16(ahi, bl, accB, 0, 0, 0);
    accA = __builtin_amdgcn_mfma_f32_32x32x16_bf16(alo, bh, accA, 0, 0, 0);

    a0 = p0; a1 = p1; p0 = n0; p1 = n1; bh = nbh; bl = nbl;
  }

#pragma unroll
  for (int i = 0; i < 16; ++i) accA[i] += accB[i];

  // C layout: col(seq)=lane&31, row=(r&3)+8*(r>>2)+4*half
  unsigned long long best = 0ull;
#pragma unroll
  for (int r = 0; r < 16; ++r) {
    int row = (r & 3) + 8 * (r >> 2) + 4 * half;
    int v = tile * 32 + row;
    if (v < VOCAB) {
      unsigned u = __float_as_uint(accA[r]);
      u = (u & 0x80000000u) ? ~u : (u | 0x80000000u);
      unsigned long long key = ((unsigned long long)u << 32) | (unsigned)(~v);
      if (key > best) best = key;
    }
  }
  unsigned long long o = __shfl_xor(best, 32, 64);
  if (o > best) best = o;
  if (half == 0) wbest[(size_t)tile * 32 + r32] = best;
}

// 32 blocks x 256: block = seq; scan NT tile-keys, first-occurrence tie-break.
__global__ __launch_bounds__(256) void k_final(
    const unsigned long long* __restrict__ wbest, int* __restrict__ out) {
  int s = blockIdx.x;
  unsigned long long best = 0ull;
  for (int i = threadIdx.x; i < NT; i += 256) {
    unsigned long long k = wbest[(size_t)i * 32 + s];
    if (k > best) best = k;
  }
#pragma unroll
  for (int off = 32; off > 0; off >>= 1) {
    unsigned long long o = __shfl_xor(best, off, 64);
    if (o > best) best = o;
  }
  __shared__ unsigned long long lred[4];
  if ((threadIdx.x & 63) == 0) lred[threadIdx.x >> 6] = best;
  __syncthreads();
  if (threadIdx.x == 0) {
#pragma unroll
    for (int i = 1; i < 4; ++i) if (lred[i] > best) best = lred[i];
    out[s] = (int)(~(unsigned)(best & 0xFFFFFFFFull));
  }
}

extern "C" void kernel_launch(void* const* d_in, const int* in_sizes, int n_in,
                              void* d_out, int out_size, void* d_ws, size_t ws_size,
                              hipStream_t stream) {
  const float* hs  = (const float*)d_in[0];   // [16384][4096] f32
  const float* W   = (const float*)d_in[1];   // [50257][4096] f32
  const int* lens  = (const int*)d_in[2];     // [32] i32

  char* ws = (char*)d_ws;
  int* idx = (int*)ws;
  short* hBh = (short*)(ws + 4096);
  short* hBl = (short*)(ws + 266240);
  unsigned long long* wbest = (unsigned long long*)(ws + 528384);
  int* out = (int*)d_out;

  k_prep<<<1, 64, 0, stream>>>(lens, idx);
  k_gather<<<256, 512, 0, stream>>>(hs, idx, hBh, hBl);
  k_mfma<<<NT, 64, 0, stream>>>(W, hBh, hBl, wbest);
  k_final<<<NUM_SEQS, 256, 0, stream>>>(wbest, out);
}